// Round 5
// baseline (301.877 us; speedup 1.0000x reference)
//
#include <hip/hip_runtime.h>
#include <math.h>

#define NN 16384      // B*N total nodes
#define NPB 4096      // nodes per batch
#define KCAP 128      // survivor capacity per wave (expected ~20 global)
#define TS 512        // kNN candidate tile size (LDS 16KB -> 8 blocks/CU)

__device__ __forceinline__ float gelu_f(float v){
  return 0.5f*v*(1.0f+erff(v*0.70710678118654752440f));
}

// ascending-by-lane bitonic sort of one u64 per lane across the 64-lane wave
__device__ __forceinline__ unsigned long long bsort64(unsigned long long v, int lane){
#pragma unroll
  for (int k=2;k<=64;k<<=1){
#pragma unroll
    for (int j=k>>1;j>0;j>>=1){
      const unsigned long long o = __shfl_xor(v, j);
      const bool keepMin = ((lane & k) == 0) == ((lane & j) == 0);
      const unsigned long long mn = v < o ? v : o;
      const unsigned long long mx = v < o ? o : v;
      v = keepMin ? mn : mx;
    }
  }
  return v;
}

// ascending-by-lane bitonic sort of one u32 per lane
__device__ __forceinline__ unsigned bsort32(unsigned v, int lane){
#pragma unroll
  for (int k=2;k<=64;k<<=1){
#pragma unroll
    for (int j=k>>1;j>0;j>>=1){
      const unsigned o = __shfl_xor(v, j);
      const bool keepMin = ((lane & k) == 0) == ((lane & j) == 0);
      const unsigned mn = v < o ? v : o;
      const unsigned mx = v < o ? o : v;
      v = keepMin ? mn : mx;
    }
  }
  return v;
}

// ---------------- pack: x[NN,6] -> PA[NN]={x0..x3}, PB[NN]={x4,x5,sq,0} ----------------
__global__ __launch_bounds__(256) void pack_k(const float* __restrict__ x,
                                              float4* __restrict__ PA, float4* __restrict__ PB){
  const int n = blockIdx.x*256 + threadIdx.x;
  const float* xr = x + (size_t)n*6;
  const float x0=xr[0],x1=xr[1],x2=xr[2],x3=xr[3],x4=xr[4],x5=xr[5];
  const float sq = x0*x0+x1*x1+x2*x2+x3*x3+x4*x4+x5*x5;
  PA[n] = make_float4(x0,x1,x2,x3);
  PB[n] = make_float4(x4,x5,sq,0.f);
}

// ---------------- kNN v5: two-pass (min-only, then recompute+compact), 17th-lane-min pivot,
//                  exact u64 bitonic finish. No per-lane key storage -> high occupancy. --------
__global__ __launch_bounds__(256) void knn_k(const float4* __restrict__ PA, const float4* __restrict__ PB,
                                             int* __restrict__ nbr){
  __shared__ float4 A4[TS];
  __shared__ float4 B4[TS];
  __shared__ unsigned skey[4][KCAP];
  __shared__ unsigned sslot[4][KCAP];
  const int t = threadIdx.x, w = t >> 6, lane = t & 63;
  const int n = blockIdx.x*4 + w;
  const int base = n & ~(NPB-1);
  const float4 qa = PA[n];
  const float4 qb = PB[n];
  const float sqn = qb.z;
  const int selfslot = n - base;

  // ---- pass 1: per-lane min d2 (self included; handled by 17th-min pivot) ----
  float mind2 = 1e30f;
#pragma unroll 1
  for (int tile=0; tile<NPB/TS; ++tile){
    __syncthreads();
    for (int i=t; i<TS; i+=256){
      A4[i] = PA[base+tile*TS+i];
      B4[i] = PB[base+tile*TS+i];
    }
    __syncthreads();
#pragma unroll
    for (int it=0; it<TS/64; ++it){
      const int s = it*64 + lane;
      const float4 a = A4[s];
      const float4 b = B4[s];
      const float dot = qa.x*a.x + qa.y*a.y + qa.z*a.z + qa.w*a.w + qb.x*b.x + qb.y*b.y;
      const float d2 = sqn + b.z - 2.0f*dot;
      mind2 = d2 < mind2 ? d2 : mind2;
    }
  }
  // map lane-min to monotone u32 (map commutes with min)
  unsigned lmk;
  {
    unsigned u = __float_as_uint(mind2);
    lmk = (u & 0x80000000u) ? ~u : (u | 0x80000000u);
  }
  // pivot: 17th smallest lane-min covers true top-16 even with self in-batch
  unsigned T = bsort32(lmk, lane);
  T = __shfl(T, 16);

  // ---- pass 2: recompute, compact survivors (key <= T, excl. self) ----
  int cnt = 0;
#pragma unroll 1
  for (int tile=0; tile<NPB/TS; ++tile){
    __syncthreads();
    for (int i=t; i<TS; i+=256){
      A4[i] = PA[base+tile*TS+i];
      B4[i] = PB[base+tile*TS+i];
    }
    __syncthreads();
#pragma unroll
    for (int it=0; it<TS/64; ++it){
      const int s = it*64 + lane;
      const float4 a = A4[s];
      const float4 b = B4[s];
      const float dot = qa.x*a.x + qa.y*a.y + qa.z*a.z + qa.w*a.w + qb.x*b.x + qb.y*b.y;
      const float d2 = sqn + b.z - 2.0f*dot;
      unsigned u = __float_as_uint(d2);
      u = (u & 0x80000000u) ? ~u : (u | 0x80000000u);
      const int slot = tile*TS + s;
      if (slot == selfslot) u = 0xFFFFFFFFu;
      const bool p = u <= T;
      const unsigned long long bb = __ballot(p);
      if (p){
        const int pos = cnt + (int)__popcll(bb & ((1ull << lane) - 1ull));
        if (pos < KCAP){ skey[w][pos] = u; sslot[w][pos] = (unsigned)slot; }
      }
      cnt += (int)__popcll(bb);
    }
  }
  if (cnt > KCAP) cnt = KCAP;

  // final: exact top-16 over survivors (u64 = key||slot, ascending, slot tie-break)
  unsigned long long vbest;
  {
    unsigned long long v = ~0ull;
    if (lane < cnt) v = ((unsigned long long)skey[w][lane] << 32) | sslot[w][lane];
    vbest = bsort64(v, lane);
  }
  for (int c=1; c*64 < cnt; ++c){   // cold path (cnt>64 ~ never)
    const int i = c*64 + lane;
    unsigned long long v = ~0ull;
    if (i < cnt) v = ((unsigned long long)skey[w][i] << 32) | sslot[w][i];
    v = bsort64(v, lane);
    const unsigned long long r = __shfl(v, 63-lane);
    vbest = vbest < r ? vbest : r;     // bitonic sequence of the 64 smallest
#pragma unroll
    for (int j=32;j>0;j>>=1){          // cleanup merge, ascending
      const unsigned long long o = __shfl_xor(vbest, j);
      const bool keepMin = (lane & j) == 0;
      const unsigned long long mn = vbest < o ? vbest : o;
      const unsigned long long mx = vbest < o ? o : vbest;
      vbest = keepMin ? mn : mx;
    }
  }
  if (lane < 16) nbr[n*16 + lane] = base + (int)(vbest & 0xFFFFFFFFull);
}

// ---------------- layer-1 GEMM: x[NN,6] @ W1[6,256] ----------------
__global__ __launch_bounds__(256) void gemm_in6(const float* __restrict__ x, const float* __restrict__ W,
                                                float* __restrict__ h){
  const int t = blockIdx.x*256 + threadIdx.x;  // over NN*64
  const int n = t >> 6, cg = t & 63;
  const float* xr = x + n*6;
  float xv[6];
#pragma unroll
  for (int d=0; d<6; d++) xv[d] = xr[d];
  float4 acc = make_float4(0.f,0.f,0.f,0.f);
#pragma unroll
  for (int d=0; d<6; d++){
    const float4 wv = *(const float4*)(W + d*256 + cg*4);
    acc.x += xv[d]*wv.x; acc.y += xv[d]*wv.y; acc.z += xv[d]*wv.z; acc.w += xv[d]*wv.w;
  }
  *(float4*)(h + n*256 + cg*4) = acc;
}

// ---------------- residual: y[NN,128] += x@res_W + res_b ----------------
__global__ __launch_bounds__(256) void res_k(const float* __restrict__ x, const float* __restrict__ W,
                                             const float* __restrict__ b, float* __restrict__ y){
  const int t = blockIdx.x*256 + threadIdx.x;  // over NN*128
  const int n = t >> 7, c = t & 127;
  const float* xr = x + n*6;
  float acc = b[c];
#pragma unroll
  for (int d=0; d<6; d++) acc += xr[d]*W[d*128 + c];
  y[t] += acc;
}

// ---------------- attention logits: als/ald [NN,HEADS] ----------------
template<int HEADS, int C>
__global__ __launch_bounds__(256) void al_k(const float* __restrict__ h, const float* __restrict__ asrc,
                                            const float* __restrict__ adst, float* __restrict__ als,
                                            float* __restrict__ ald){
  const int t = blockIdx.x*256 + threadIdx.x;  // over NN*HEADS
  const int n = t / HEADS, hd = t % HEADS;
  const float* hp = h + (n*HEADS + hd)*C;
  const float* ap = asrc + hd*C;
  const float* dp = adst + hd*C;
  float s=0.f, d=0.f;
#pragma unroll 4
  for (int c=0;c<C;c+=4){
    const float4 v = *(const float4*)(hp+c);
    const float4 a = *(const float4*)(ap+c);
    const float4 b = *(const float4*)(dp+c);
    s += v.x*a.x + v.y*a.y + v.z*a.z + v.w*a.w;
    d += v.x*b.x + v.y*b.y + v.z*b.z + v.w*b.w;
  }
  als[t] = s; ald[t] = d;
}

// ---------------- GAT aggregation: one wave per node, 17-way softmax gather ----------------
template<int HEADS, int C>
__global__ __launch_bounds__(256) void agg_k(const float* __restrict__ h, const float* __restrict__ als,
                                             const float* __restrict__ ald, const int* __restrict__ nbr,
                                             const float* __restrict__ bias, float* __restrict__ out){
  constexpr int CT = HEADS*C;
  constexpr int F  = CT/64;
  const int w = threadIdx.x >> 6, lane = threadIdx.x & 63;
  const int n = blockIdx.x*4 + w;
  const int head = (lane*F)/C;
  const int col  = lane*F;
  const int nb = nbr[n*16 + (lane & 15)];
  const float aldn = ald[n*HEADS + head];
  float e[17];
#pragma unroll
  for (int j=0;j<17;j++){
    const int sj = (j<16) ? __shfl(nb, j) : n;
    const float v = als[sj*HEADS + head] + aldn;
    e[j] = v > 0.f ? v : 0.2f*v;
  }
  float mx = e[0];
#pragma unroll
  for (int j=1;j<17;j++) mx = fmaxf(mx, e[j]);
  float den = 0.f;
#pragma unroll
  for (int j=0;j<17;j++){ e[j] = expf(e[j]-mx); den += e[j]; }
  float acc[F];
#pragma unroll
  for (int f=0;f<F;f++) acc[f]=0.f;
#pragma unroll
  for (int j=0;j<17;j++){
    const int sj = (j<16) ? __shfl(nb, j) : n;
    const float* hp = h + sj*CT + col;
    if constexpr (F==4){
      const float4 v = *(const float4*)hp;
      acc[0] += e[j]*v.x; acc[1] += e[j]*v.y; acc[2] += e[j]*v.z; acc[3] += e[j]*v.w;
    } else {
      const float2 v = *(const float2*)hp;
      acc[0] += e[j]*v.x; acc[1] += e[j]*v.y;
    }
  }
  const float inv = 1.f/den;
  if constexpr (F==4){
    float4 o;
    o.x = gelu_f(acc[0]*inv + bias[col+0]);
    o.y = gelu_f(acc[1]*inv + bias[col+1]);
    o.z = gelu_f(acc[2]*inv + bias[col+2]);
    o.w = gelu_f(acc[3]*inv + bias[col+3]);
    *(float4*)(out + n*CT + col) = o;
  } else {
    float2 o;
    o.x = gelu_f(acc[0]*inv + bias[col+0]);
    o.y = gelu_f(acc[1]*inv + bias[col+1]);
    *(float2*)(out + n*CT + col) = o;
  }
}

// ---------------- generic fp32 tiled GEMM: [M,KC] @ [KC,NC], BM=128 BN=64 BK=32 ----------------
template<int KC, int NC, bool BIAS, bool GELU>
__global__ __launch_bounds__(256) void gemm_k(const float* __restrict__ A, const float* __restrict__ B,
                                              const float* __restrict__ bias, float* __restrict__ C){
  __shared__ float Ast[32][132];   // A chunk transposed: Ast[k][row]
  __shared__ float Bs[32][64];
  const int t  = threadIdx.x;
  const int r0 = blockIdx.x*128;
  const int c0 = blockIdx.y*64;
  const int ty = t >> 4, tx = t & 15;
  const int ar = t >> 1, ac = (t & 1)*16;
  const int br = t >> 3, bc = (t & 7)*8;
  float acc[8][4];
#pragma unroll
  for (int i=0;i<8;i++)
#pragma unroll
    for (int j=0;j<4;j++) acc[i][j] = 0.f;

#pragma unroll 1
  for (int kc=0; kc<KC; kc+=32){
    const float* Ap = A + (size_t)(r0+ar)*KC + kc + ac;
    float4 av[4];
#pragma unroll
    for (int u=0;u<4;u++) av[u] = *(const float4*)(Ap + u*4);
#pragma unroll
    for (int u=0;u<4;u++){
      Ast[ac+u*4+0][ar] = av[u].x;
      Ast[ac+u*4+1][ar] = av[u].y;
      Ast[ac+u*4+2][ar] = av[u].z;
      Ast[ac+u*4+3][ar] = av[u].w;
    }
    const float* Bp = B + (size_t)(kc+br)*NC + c0 + bc;
    *(float4*)&Bs[br][bc]   = *(const float4*)Bp;
    *(float4*)&Bs[br][bc+4] = *(const float4*)(Bp+4);
    __syncthreads();
#pragma unroll
    for (int k=0;k<32;k++){
      const float4 a0 = *(const float4*)&Ast[k][ty*8];
      const float4 a1 = *(const float4*)&Ast[k][ty*8+4];
      const float4 bv = *(const float4*)&Bs[k][tx*4];
      const float avr[8] = {a0.x,a0.y,a0.z,a0.w,a1.x,a1.y,a1.z,a1.w};
      const float bbr[4] = {bv.x,bv.y,bv.z,bv.w};
#pragma unroll
      for (int i=0;i<8;i++)
#pragma unroll
        for (int j=0;j<4;j++)
          acc[i][j] += avr[i]*bbr[j];
    }
    __syncthreads();
  }
#pragma unroll
  for (int i=0;i<8;i++){
    const int r = r0 + ty*8 + i;
    float vv[4];
#pragma unroll
    for (int j=0;j<4;j++){
      float v = acc[i][j];
      if constexpr (BIAS) v += bias[c0 + tx*4 + j];
      if constexpr (GELU) v = gelu_f(v);
      vv[j] = v;
    }
    *(float4*)(C + (size_t)r*NC + c0 + tx*4) = make_float4(vv[0],vv[1],vv[2],vv[3]);
  }
}

// ---------------- final tiny GEMM: [NN,64] @ [64,6] + b ----------------
__global__ __launch_bounds__(256) void m3_k(const float* __restrict__ A, const float* __restrict__ W,
                                            const float* __restrict__ bias, float* __restrict__ out){
  __shared__ float Wl[64*6];
  __shared__ float bl[6];
  const int t = threadIdx.x;
  for (int i=t; i<384; i+=256) Wl[i] = W[i];
  if (t < 6) bl[t] = bias[t];
  __syncthreads();
  const int n = blockIdx.x*256 + t;
  const float* ap = A + n*64;
  float acc[6] = {0.f,0.f,0.f,0.f,0.f,0.f};
  for (int k=0;k<64;k+=4){
    const float4 v = *(const float4*)(ap+k);
    const float vr[4] = {v.x,v.y,v.z,v.w};
#pragma unroll
    for (int u=0;u<4;u++)
#pragma unroll
      for (int j=0;j<6;j++)
        acc[j] += vr[u]*Wl[(k+u)*6+j];
  }
#pragma unroll
  for (int j=0;j<6;j++) out[n*6+j] = acc[j] + bl[j];
}

extern "C" void kernel_launch(void* const* d_in, const int* in_sizes, int n_in,
                              void* d_out, int out_size, void* d_ws, size_t ws_size,
                              hipStream_t stream){
  (void)in_sizes; (void)n_in; (void)out_size; (void)ws_size;
  const float* x      = (const float*)d_in[0];
  const float* W1     = (const float*)d_in[1];
  const float* a_src1 = (const float*)d_in[2];
  const float* a_dst1 = (const float*)d_in[3];
  const float* b1     = (const float*)d_in[4];
  const float* W2     = (const float*)d_in[5];
  const float* a_src2 = (const float*)d_in[6];
  const float* a_dst2 = (const float*)d_in[7];
  const float* b2     = (const float*)d_in[8];
  const float* W3     = (const float*)d_in[9];
  const float* a_src3 = (const float*)d_in[10];
  const float* a_dst3 = (const float*)d_in[11];
  const float* b3     = (const float*)d_in[12];
  const float* res_W  = (const float*)d_in[13];
  const float* res_b  = (const float*)d_in[14];
  const float* m1_W   = (const float*)d_in[15];
  const float* m1_b   = (const float*)d_in[16];
  const float* m2_W   = (const float*)d_in[17];
  const float* m2_b   = (const float*)d_in[18];
  const float* m3_W   = (const float*)d_in[19];
  const float* m3_b   = (const float*)d_in[20];
  float* out = (float*)d_out;

  char* wsb = (char*)d_ws;
  int*   nbr = (int*)wsb;                                   // 1 MB
  float* H   = (float*)(wsb + (1u<<20));                    // 16 MB
  float* Y   = (float*)(wsb + (1u<<20) + (16u<<20));        // 16 MB
  float* ALS = (float*)(wsb + (1u<<20) + (32u<<20));        // 256 KB
  float* ALD = ALS + NN*4;                                  // 256 KB
  float4* PA = (float4*)(wsb + (1u<<20) + (32u<<20) + (512u<<10)); // 256 KB
  float4* PB = PA + NN;                                            // 256 KB

  pack_k<<<NN/256, 256, 0, stream>>>(x, PA, PB);
  knn_k<<<NN/4, 256, 0, stream>>>(PA, PB, nbr);

  // GAT layer 1: 6 -> 4x64
  gemm_in6<<<NN*64/256, 256, 0, stream>>>(x, W1, H);
  al_k<4,64><<<NN*4/256, 256, 0, stream>>>(H, a_src1, a_dst1, ALS, ALD);
  agg_k<4,64><<<NN/4, 256, 0, stream>>>(H, ALS, ALD, nbr, b1, Y);

  // GAT layer 2: 256 -> 4x64
  gemm_k<256,256,false,false><<<dim3(NN/128, 4), 256, 0, stream>>>(Y, W2, nullptr, H);
  al_k<4,64><<<NN*4/256, 256, 0, stream>>>(H, a_src2, a_dst2, ALS, ALD);
  agg_k<4,64><<<NN/4, 256, 0, stream>>>(H, ALS, ALD, nbr, b2, Y);

  // GAT layer 3: 256 -> 1x128
  gemm_k<256,128,false,false><<<dim3(NN/128, 2), 256, 0, stream>>>(Y, W3, nullptr, H);
  al_k<1,128><<<NN/256, 256, 0, stream>>>(H, a_src3, a_dst3, ALS, ALD);
  agg_k<1,128><<<NN/4, 256, 0, stream>>>(H, ALS, ALD, nbr, b3, Y);

  // residual + MLP
  res_k<<<NN*128/256, 256, 0, stream>>>(x, res_W, res_b, Y);
  gemm_k<128,128,true,true><<<dim3(NN/128, 2), 256, 0, stream>>>(Y, m1_W, m1_b, H);
  gemm_k<128,64,true,true><<<dim3(NN/128, 1), 256, 0, stream>>>(H, m2_W, m2_b, Y);
  m3_k<<<NN/256, 256, 0, stream>>>(Y, m3_W, m3_b, out);
}

// Round 6
// 284.712 us; speedup vs baseline: 1.0603x; 1.0603x over previous
//
#include <hip/hip_runtime.h>
#include <math.h>

#define NN 16384      // B*N total nodes
#define NPB 4096      // nodes per batch
#define KCAP 128      // survivor capacity per wave (expected ~20)
#define TS 512        // kNN candidate tile size (LDS 20480 B -> 8 blocks/CU)

__device__ __forceinline__ float gelu_f(float v){
  return 0.5f*v*(1.0f+erff(v*0.70710678118654752440f));
}

// monotone float->uint map: order-preserving for all finite values
__device__ __forceinline__ unsigned fmap(float d2){
  unsigned u = __float_as_uint(d2);
  return u ^ ((unsigned)((int)u >> 31) | 0x80000000u);
}

// distance key: one canonical inlined form so pass-1 and the survivor recompute
// produce bit-identical values
__device__ __forceinline__ unsigned dkey(const float4 qa, const float4 qb, const float sqn,
                                         const float4 a, const float4 b){
  const float dot = qa.x*a.x + qa.y*a.y + qa.z*a.z + qa.w*a.w + qb.x*b.x + qb.y*b.y;
  const float d2 = sqn + b.z - 2.0f*dot;
  return fmap(d2);
}

// ascending-by-lane bitonic sort of one u64 per lane across the 64-lane wave
__device__ __forceinline__ unsigned long long bsort64(unsigned long long v, int lane){
#pragma unroll
  for (int k=2;k<=64;k<<=1){
#pragma unroll
    for (int j=k>>1;j>0;j>>=1){
      const unsigned long long o = __shfl_xor(v, j);
      const bool keepMin = ((lane & k) == 0) == ((lane & j) == 0);
      const unsigned long long mn = v < o ? v : o;
      const unsigned long long mx = v < o ? o : v;
      v = keepMin ? mn : mx;
    }
  }
  return v;
}

// ascending-by-lane bitonic sort of one u32 per lane
__device__ __forceinline__ unsigned bsort32(unsigned v, int lane){
#pragma unroll
  for (int k=2;k<=64;k<<=1){
#pragma unroll
    for (int j=k>>1;j>0;j>>=1){
      const unsigned o = __shfl_xor(v, j);
      const bool keepMin = ((lane & k) == 0) == ((lane & j) == 0);
      const unsigned mn = v < o ? v : o;
      const unsigned mx = v < o ? o : v;
      v = keepMin ? mn : mx;
    }
  }
  return v;
}

// ---------------- pack: x[NN,6] -> PA[NN]={x0..x3}, PB[NN]={x4,x5,sq,0} ----------------
__global__ __launch_bounds__(256) void pack_k(const float* __restrict__ x,
                                              float4* __restrict__ PA, float4* __restrict__ PB){
  const int n = blockIdx.x*256 + threadIdx.x;
  const float* xr = x + (size_t)n*6;
  const float x0=xr[0],x1=xr[1],x2=xr[2],x3=xr[3],x4=xr[4],x5=xr[5];
  const float sq = x0*x0+x1*x1+x2*x2+x3*x3+x4*x4+x5*x5;
  PA[n] = make_float4(x0,x1,x2,x3);
  PB[n] = make_float4(x4,x5,sq,0.f);
}

// ---------------- kNN v6: single pass, 16-bit packed keys in registers (kp[32]),
//                  exact full-precision lane-min pivot, ballot compact on truncated key,
//                  exact fp32 recompute for ~20 survivors + u64 bitonic finish ----------------
__global__ __launch_bounds__(256, 8) void knn_k(const float4* __restrict__ PA, const float4* __restrict__ PB,
                                                int* __restrict__ nbr){
  __shared__ float4 A4[TS];
  __shared__ float4 B4[TS];
  __shared__ unsigned skey[4][KCAP];
  __shared__ unsigned sslot[4][KCAP];
  const int t = threadIdx.x, w = t >> 6, lane = t & 63;
  const int n = blockIdx.x*4 + w;
  const int base = n & ~(NPB-1);
  const float4 qa = PA[n];
  const float4 qb = PB[n];
  const float sqn = qb.z;
  const int selfslot = n - base;

  // single pass: distances -> 16-bit packed keys in regs + full-precision lane min
  unsigned kp[32];
  unsigned minu = 0xFFFFFFFFu;
#pragma unroll
  for (int tile=0; tile<NPB/TS; ++tile){
    __syncthreads();   // all waves done reading previous tile
#pragma unroll
    for (int i=t; i<TS; i+=256){
      A4[i] = PA[base+tile*TS+i];
      B4[i] = PB[base+tile*TS+i];
    }
    __syncthreads();
    unsigned lo = 0;
#pragma unroll
    for (int it=0; it<TS/64; ++it){
      const int s = it*64 + lane;
      unsigned u = dkey(qa, qb, sqn, A4[s], B4[s]);
      if (tile*TS + s == selfslot) u = 0xFFFFFFFFu;   // exclude self
      minu = u < minu ? u : minu;
      if ((it & 1) == 0) lo = u >> 16;
      else               kp[(tile*(TS/64)+it)>>1] = lo | (u & 0xFFFF0000u);
    }
  }

  // pivot: 16th smallest lane-min (self excluded in-pass) >= true 16th key
  unsigned T = bsort32(minu, lane);
  T = __shfl(T, 15);
  const unsigned T16 = T >> 16;

  // compact survivors (truncated key <= T16 -> superset of true top-16)
  int cnt = 0;
#pragma unroll
  for (int q=0; q<64; ++q){
    const unsigned k16 = (kp[q>>1] >> ((q&1)*16)) & 0xFFFFu;
    const bool p = k16 <= T16;
    const unsigned long long bb = __ballot(p);
    if (p){
      const int pos = cnt + (int)__popcll(bb & ((1ull << lane) - 1ull));
      if (pos < KCAP){
        // q = tile*8 + it ; slot = tile*TS + it*64 + lane
        sslot[w][pos] = (unsigned)((q>>3)*TS + (q&7)*64 + lane);
      }
    }
    cnt += (int)__popcll(bb);
  }
  if (cnt > KCAP) cnt = KCAP;

  // recompute exact keys for survivors (identical expression -> identical bits)
  for (int i=lane; i<cnt; i+=64){
    const int slot = (int)sslot[w][i];
    unsigned u = dkey(qa, qb, sqn, PA[base+slot], PB[base+slot]);
    skey[w][i] = u;
  }

  // final: exact top-16 over survivors (u64 = key||slot, ascending, slot tie-break)
  unsigned long long vbest;
  {
    unsigned long long v = ~0ull;
    if (lane < cnt) v = ((unsigned long long)skey[w][lane] << 32) | sslot[w][lane];
    vbest = bsort64(v, lane);
  }
  for (int c=1; c*64 < cnt; ++c){   // cold path (cnt>64 ~ never)
    const int i = c*64 + lane;
    unsigned long long v = ~0ull;
    if (i < cnt) v = ((unsigned long long)skey[w][i] << 32) | sslot[w][i];
    v = bsort64(v, lane);
    const unsigned long long r = __shfl(v, 63-lane);
    vbest = vbest < r ? vbest : r;     // bitonic sequence of the 64 smallest
#pragma unroll
    for (int j=32;j>0;j>>=1){          // cleanup merge, ascending
      const unsigned long long o = __shfl_xor(vbest, j);
      const bool keepMin = (lane & j) == 0;
      const unsigned long long mn = vbest < o ? vbest : o;
      const unsigned long long mx = vbest < o ? o : vbest;
      vbest = keepMin ? mn : mx;
    }
  }
  if (lane < 16) nbr[n*16 + lane] = base + (int)(vbest & 0xFFFFFFFFull);
}

// ---------------- layer-1 GEMM: x[NN,6] @ W1[6,256] ----------------
__global__ __launch_bounds__(256) void gemm_in6(const float* __restrict__ x, const float* __restrict__ W,
                                                float* __restrict__ h){
  const int t = blockIdx.x*256 + threadIdx.x;  // over NN*64
  const int n = t >> 6, cg = t & 63;
  const float* xr = x + n*6;
  float xv[6];
#pragma unroll
  for (int d=0; d<6; d++) xv[d] = xr[d];
  float4 acc = make_float4(0.f,0.f,0.f,0.f);
#pragma unroll
  for (int d=0; d<6; d++){
    const float4 wv = *(const float4*)(W + d*256 + cg*4);
    acc.x += xv[d]*wv.x; acc.y += xv[d]*wv.y; acc.z += xv[d]*wv.z; acc.w += xv[d]*wv.w;
  }
  *(float4*)(h + n*256 + cg*4) = acc;
}

// ---------------- residual: y[NN,128] += x@res_W + res_b ----------------
__global__ __launch_bounds__(256) void res_k(const float* __restrict__ x, const float* __restrict__ W,
                                             const float* __restrict__ b, float* __restrict__ y){
  const int t = blockIdx.x*256 + threadIdx.x;  // over NN*128
  const int n = t >> 7, c = t & 127;
  const float* xr = x + n*6;
  float acc = b[c];
#pragma unroll
  for (int d=0; d<6; d++) acc += xr[d]*W[d*128 + c];
  y[t] += acc;
}

// ---------------- attention logits: als/ald [NN,HEADS] ----------------
template<int HEADS, int C>
__global__ __launch_bounds__(256) void al_k(const float* __restrict__ h, const float* __restrict__ asrc,
                                            const float* __restrict__ adst, float* __restrict__ als,
                                            float* __restrict__ ald){
  const int t = blockIdx.x*256 + threadIdx.x;  // over NN*HEADS
  const int n = t / HEADS, hd = t % HEADS;
  const float* hp = h + (n*HEADS + hd)*C;
  const float* ap = asrc + hd*C;
  const float* dp = adst + hd*C;
  float s=0.f, d=0.f;
#pragma unroll 4
  for (int c=0;c<C;c+=4){
    const float4 v = *(const float4*)(hp+c);
    const float4 a = *(const float4*)(ap+c);
    const float4 b = *(const float4*)(dp+c);
    s += v.x*a.x + v.y*a.y + v.z*a.z + v.w*a.w;
    d += v.x*b.x + v.y*b.y + v.z*b.z + v.w*b.w;
  }
  als[t] = s; ald[t] = d;
}

// ---------------- GAT aggregation: one wave per node, 17-way softmax gather ----------------
template<int HEADS, int C>
__global__ __launch_bounds__(256) void agg_k(const float* __restrict__ h, const float* __restrict__ als,
                                             const float* __restrict__ ald, const int* __restrict__ nbr,
                                             const float* __restrict__ bias, float* __restrict__ out){
  constexpr int CT = HEADS*C;
  constexpr int F  = CT/64;
  const int w = threadIdx.x >> 6, lane = threadIdx.x & 63;
  const int n = blockIdx.x*4 + w;
  const int head = (lane*F)/C;
  const int col  = lane*F;
  const int nb = nbr[n*16 + (lane & 15)];
  const float aldn = ald[n*HEADS + head];
  float e[17];
#pragma unroll
  for (int j=0;j<17;j++){
    const int sj = (j<16) ? __shfl(nb, j) : n;
    const float v = als[sj*HEADS + head] + aldn;
    e[j] = v > 0.f ? v : 0.2f*v;
  }
  float mx = e[0];
#pragma unroll
  for (int j=1;j<17;j++) mx = fmaxf(mx, e[j]);
  float den = 0.f;
#pragma unroll
  for (int j=0;j<17;j++){ e[j] = expf(e[j]-mx); den += e[j]; }
  float acc[F];
#pragma unroll
  for (int f=0;f<F;f++) acc[f]=0.f;
#pragma unroll
  for (int j=0;j<17;j++){
    const int sj = (j<16) ? __shfl(nb, j) : n;
    const float* hp = h + sj*CT + col;
    if constexpr (F==4){
      const float4 v = *(const float4*)hp;
      acc[0] += e[j]*v.x; acc[1] += e[j]*v.y; acc[2] += e[j]*v.z; acc[3] += e[j]*v.w;
    } else {
      const float2 v = *(const float2*)hp;
      acc[0] += e[j]*v.x; acc[1] += e[j]*v.y;
    }
  }
  const float inv = 1.f/den;
  if constexpr (F==4){
    float4 o;
    o.x = gelu_f(acc[0]*inv + bias[col+0]);
    o.y = gelu_f(acc[1]*inv + bias[col+1]);
    o.z = gelu_f(acc[2]*inv + bias[col+2]);
    o.w = gelu_f(acc[3]*inv + bias[col+3]);
    *(float4*)(out + n*CT + col) = o;
  } else {
    float2 o;
    o.x = gelu_f(acc[0]*inv + bias[col+0]);
    o.y = gelu_f(acc[1]*inv + bias[col+1]);
    *(float2*)(out + n*CT + col) = o;
  }
}

// ---------------- generic fp32 tiled GEMM: [M,KC] @ [KC,NC], BM=128 BN=64 BK=32 ----------------
template<int KC, int NC, bool BIAS, bool GELU>
__global__ __launch_bounds__(256) void gemm_k(const float* __restrict__ A, const float* __restrict__ B,
                                              const float* __restrict__ bias, float* __restrict__ C){
  __shared__ float Ast[32][132];   // A chunk transposed: Ast[k][row]
  __shared__ float Bs[32][64];
  const int t  = threadIdx.x;
  const int r0 = blockIdx.x*128;
  const int c0 = blockIdx.y*64;
  const int ty = t >> 4, tx = t & 15;
  const int ar = t >> 1, ac = (t & 1)*16;
  const int br = t >> 3, bc = (t & 7)*8;
  float acc[8][4];
#pragma unroll
  for (int i=0;i<8;i++)
#pragma unroll
    for (int j=0;j<4;j++) acc[i][j] = 0.f;

#pragma unroll 1
  for (int kc=0; kc<KC; kc+=32){
    const float* Ap = A + (size_t)(r0+ar)*KC + kc + ac;
    float4 av[4];
#pragma unroll
    for (int u=0;u<4;u++) av[u] = *(const float4*)(Ap + u*4);
#pragma unroll
    for (int u=0;u<4;u++){
      Ast[ac+u*4+0][ar] = av[u].x;
      Ast[ac+u*4+1][ar] = av[u].y;
      Ast[ac+u*4+2][ar] = av[u].z;
      Ast[ac+u*4+3][ar] = av[u].w;
    }
    const float* Bp = B + (size_t)(kc+br)*NC + c0 + bc;
    *(float4*)&Bs[br][bc]   = *(const float4*)Bp;
    *(float4*)&Bs[br][bc+4] = *(const float4*)(Bp+4);
    __syncthreads();
#pragma unroll
    for (int k=0;k<32;k++){
      const float4 a0 = *(const float4*)&Ast[k][ty*8];
      const float4 a1 = *(const float4*)&Ast[k][ty*8+4];
      const float4 bv = *(const float4*)&Bs[k][tx*4];
      const float avr[8] = {a0.x,a0.y,a0.z,a0.w,a1.x,a1.y,a1.z,a1.w};
      const float bbr[4] = {bv.x,bv.y,bv.z,bv.w};
#pragma unroll
      for (int i=0;i<8;i++)
#pragma unroll
        for (int j=0;j<4;j++)
          acc[i][j] += avr[i]*bbr[j];
    }
    __syncthreads();
  }
#pragma unroll
  for (int i=0;i<8;i++){
    const int r = r0 + ty*8 + i;
    float vv[4];
#pragma unroll
    for (int j=0;j<4;j++){
      float v = acc[i][j];
      if constexpr (BIAS) v += bias[c0 + tx*4 + j];
      if constexpr (GELU) v = gelu_f(v);
      vv[j] = v;
    }
    *(float4*)(C + (size_t)r*NC + c0 + tx*4) = make_float4(vv[0],vv[1],vv[2],vv[3]);
  }
}

// ---------------- final tiny GEMM: [NN,64] @ [64,6] + b ----------------
__global__ __launch_bounds__(256) void m3_k(const float* __restrict__ A, const float* __restrict__ W,
                                            const float* __restrict__ bias, float* __restrict__ out){
  __shared__ float Wl[64*6];
  __shared__ float bl[6];
  const int t = threadIdx.x;
  for (int i=t; i<384; i+=256) Wl[i] = W[i];
  if (t < 6) bl[t] = bias[t];
  __syncthreads();
  const int n = blockIdx.x*256 + t;
  const float* ap = A + n*64;
  float acc[6] = {0.f,0.f,0.f,0.f,0.f,0.f};
  for (int k=0;k<64;k+=4){
    const float4 v = *(const float4*)(ap+k);
    const float vr[4] = {v.x,v.y,v.z,v.w};
#pragma unroll
    for (int u=0;u<4;u++)
#pragma unroll
      for (int j=0;j<6;j++)
        acc[j] += vr[u]*Wl[(k+u)*6+j];
  }
#pragma unroll
  for (int j=0;j<6;j++) out[n*6+j] = acc[j] + bl[j];
}

extern "C" void kernel_launch(void* const* d_in, const int* in_sizes, int n_in,
                              void* d_out, int out_size, void* d_ws, size_t ws_size,
                              hipStream_t stream){
  (void)in_sizes; (void)n_in; (void)out_size; (void)ws_size;
  const float* x      = (const float*)d_in[0];
  const float* W1     = (const float*)d_in[1];
  const float* a_src1 = (const float*)d_in[2];
  const float* a_dst1 = (const float*)d_in[3];
  const float* b1     = (const float*)d_in[4];
  const float* W2     = (const float*)d_in[5];
  const float* a_src2 = (const float*)d_in[6];
  const float* a_dst2 = (const float*)d_in[7];
  const float* b2     = (const float*)d_in[8];
  const float* W3     = (const float*)d_in[9];
  const float* a_src3 = (const float*)d_in[10];
  const float* a_dst3 = (const float*)d_in[11];
  const float* b3     = (const float*)d_in[12];
  const float* res_W  = (const float*)d_in[13];
  const float* res_b  = (const float*)d_in[14];
  const float* m1_W   = (const float*)d_in[15];
  const float* m1_b   = (const float*)d_in[16];
  const float* m2_W   = (const float*)d_in[17];
  const float* m2_b   = (const float*)d_in[18];
  const float* m3_W   = (const float*)d_in[19];
  const float* m3_b   = (const float*)d_in[20];
  float* out = (float*)d_out;

  char* wsb = (char*)d_ws;
  int*   nbr = (int*)wsb;                                   // 1 MB
  float* H   = (float*)(wsb + (1u<<20));                    // 16 MB
  float* Y   = (float*)(wsb + (1u<<20) + (16u<<20));        // 16 MB
  float* ALS = (float*)(wsb + (1u<<20) + (32u<<20));        // 256 KB
  float* ALD = ALS + NN*4;                                  // 256 KB
  float4* PA = (float4*)(wsb + (1u<<20) + (32u<<20) + (512u<<10)); // 256 KB
  float4* PB = PA + NN;                                            // 256 KB

  pack_k<<<NN/256, 256, 0, stream>>>(x, PA, PB);
  knn_k<<<NN/4, 256, 0, stream>>>(PA, PB, nbr);

  // GAT layer 1: 6 -> 4x64
  gemm_in6<<<NN*64/256, 256, 0, stream>>>(x, W1, H);
  al_k<4,64><<<NN*4/256, 256, 0, stream>>>(H, a_src1, a_dst1, ALS, ALD);
  agg_k<4,64><<<NN/4, 256, 0, stream>>>(H, ALS, ALD, nbr, b1, Y);

  // GAT layer 2: 256 -> 4x64
  gemm_k<256,256,false,false><<<dim3(NN/128, 4), 256, 0, stream>>>(Y, W2, nullptr, H);
  al_k<4,64><<<NN*4/256, 256, 0, stream>>>(H, a_src2, a_dst2, ALS, ALD);
  agg_k<4,64><<<NN/4, 256, 0, stream>>>(H, ALS, ALD, nbr, b2, Y);

  // GAT layer 3: 256 -> 1x128
  gemm_k<256,128,false,false><<<dim3(NN/128, 2), 256, 0, stream>>>(Y, W3, nullptr, H);
  al_k<1,128><<<NN/256, 256, 0, stream>>>(H, a_src3, a_dst3, ALS, ALD);
  agg_k<1,128><<<NN/4, 256, 0, stream>>>(H, ALS, ALD, nbr, b3, Y);

  // residual + MLP
  res_k<<<NN*128/256, 256, 0, stream>>>(x, res_W, res_b, Y);
  gemm_k<128,128,true,true><<<dim3(NN/128, 2), 256, 0, stream>>>(Y, m1_W, m1_b, H);
  gemm_k<128,64,true,true><<<dim3(NN/128, 1), 256, 0, stream>>>(H, m2_W, m2_b, Y);
  m3_k<<<NN/256, 256, 0, stream>>>(Y, m3_W, m3_b, out);
}

// Round 7
// 269.120 us; speedup vs baseline: 1.1217x; 1.0579x over previous
//
#include <hip/hip_runtime.h>
#include <math.h>

#define NN 16384      // B*N total nodes
#define NPB 4096      // nodes per batch
#define KCAP 128      // survivor capacity per wave (expected ~20)
#define TS 512        // kNN candidate tile size (LDS 20480 B -> 8 blocks/CU)

__device__ __forceinline__ float gelu_f(float v){
  return 0.5f*v*(1.0f+erff(v*0.70710678118654752440f));
}

// monotone float->uint map: order-preserving for all finite values
__device__ __forceinline__ unsigned fmap(float d2){
  unsigned u = __float_as_uint(d2);
  return u ^ ((unsigned)((int)u >> 31) | 0x80000000u);
}

// distance key: one canonical inlined form so pass-1 and the survivor recompute
// produce bit-identical values
__device__ __forceinline__ unsigned dkey(const float4 qa, const float4 qb, const float sqn,
                                         const float4 a, const float4 b){
  const float dot = qa.x*a.x + qa.y*a.y + qa.z*a.z + qa.w*a.w + qb.x*b.x + qb.y*b.y;
  const float d2 = sqn + b.z - 2.0f*dot;
  return fmap(d2);
}

// ascending-by-lane bitonic sort of one u64 per lane across the 64-lane wave
__device__ __forceinline__ unsigned long long bsort64(unsigned long long v, int lane){
#pragma unroll
  for (int k=2;k<=64;k<<=1){
#pragma unroll
    for (int j=k>>1;j>0;j>>=1){
      const unsigned long long o = __shfl_xor(v, j);
      const bool keepMin = ((lane & k) == 0) == ((lane & j) == 0);
      const unsigned long long mn = v < o ? v : o;
      const unsigned long long mx = v < o ? o : v;
      v = keepMin ? mn : mx;
    }
  }
  return v;
}

// ascending-by-lane bitonic sort of one u32 per lane
__device__ __forceinline__ unsigned bsort32(unsigned v, int lane){
#pragma unroll
  for (int k=2;k<=64;k<<=1){
#pragma unroll
    for (int j=k>>1;j>0;j>>=1){
      const unsigned o = __shfl_xor(v, j);
      const bool keepMin = ((lane & k) == 0) == ((lane & j) == 0);
      const unsigned mn = v < o ? v : o;
      const unsigned mx = v < o ? o : v;
      v = keepMin ? mn : mx;
    }
  }
  return v;
}

// ---------------- pack: x[NN,6] -> PA[NN]={x0..x3}, PB[NN]={x4,x5,sq,0} ----------------
__global__ __launch_bounds__(256) void pack_k(const float* __restrict__ x,
                                              float4* __restrict__ PA, float4* __restrict__ PB){
  const int n = blockIdx.x*256 + threadIdx.x;
  const float* xr = x + (size_t)n*6;
  const float x0=xr[0],x1=xr[1],x2=xr[2],x3=xr[3],x4=xr[4],x5=xr[5];
  const float sq = x0*x0+x1*x1+x2*x2+x3*x3+x4*x4+x5*x5;
  PA[n] = make_float4(x0,x1,x2,x3);
  PB[n] = make_float4(x4,x5,sq,0.f);
}

// ---------------- kNN v7: v6 structure, but launch_bounds (256,6) so kp[32] stays in
//                  VGPRs (v6's (256,8) forced a 64-VGPR cap -> full spill to scratch,
//                  134 MB/dispatch HBM round-trip). ----------------
__global__ __launch_bounds__(256, 6) void knn_k(const float4* __restrict__ PA, const float4* __restrict__ PB,
                                                int* __restrict__ nbr){
  __shared__ float4 A4[TS];
  __shared__ float4 B4[TS];
  __shared__ unsigned skey[4][KCAP];
  __shared__ unsigned sslot[4][KCAP];
  const int t = threadIdx.x, w = t >> 6, lane = t & 63;
  const int n = blockIdx.x*4 + w;
  const int base = n & ~(NPB-1);
  const float4 qa = PA[n];
  const float4 qb = PB[n];
  const float sqn = qb.z;
  const int selfslot = n - base;

  // single pass: distances -> 16-bit packed keys in regs + full-precision lane min
  unsigned kp[32];
  unsigned minu = 0xFFFFFFFFu;
#pragma unroll
  for (int tile=0; tile<NPB/TS; ++tile){
    __syncthreads();   // all waves done reading previous tile
#pragma unroll
    for (int i=t; i<TS; i+=256){
      A4[i] = PA[base+tile*TS+i];
      B4[i] = PB[base+tile*TS+i];
    }
    __syncthreads();
    unsigned lo = 0;
#pragma unroll
    for (int it=0; it<TS/64; ++it){
      const int s = it*64 + lane;
      unsigned u = dkey(qa, qb, sqn, A4[s], B4[s]);
      if (tile*TS + s == selfslot) u = 0xFFFFFFFFu;   // exclude self
      minu = u < minu ? u : minu;
      if ((it & 1) == 0) lo = u >> 16;
      else               kp[(tile*(TS/64)+it)>>1] = lo | (u & 0xFFFF0000u);
    }
  }

  // pivot: 16th smallest lane-min (self excluded in-pass) >= true 16th key
  unsigned T = bsort32(minu, lane);
  T = __shfl(T, 15);
  const unsigned T16 = T >> 16;

  // compact survivors (truncated key <= T16 -> superset of true top-16)
  int cnt = 0;
#pragma unroll
  for (int q=0; q<64; ++q){
    const unsigned k16 = (kp[q>>1] >> ((q&1)*16)) & 0xFFFFu;
    const bool p = k16 <= T16;
    const unsigned long long bb = __ballot(p);
    if (p){
      const int pos = cnt + (int)__popcll(bb & ((1ull << lane) - 1ull));
      if (pos < KCAP){
        // q = tile*8 + it ; slot = tile*TS + it*64 + lane
        sslot[w][pos] = (unsigned)((q>>3)*TS + (q&7)*64 + lane);
      }
    }
    cnt += (int)__popcll(bb);
  }
  if (cnt > KCAP) cnt = KCAP;

  // recompute exact keys for survivors (identical expression -> identical bits)
  for (int i=lane; i<cnt; i+=64){
    const int slot = (int)sslot[w][i];
    unsigned u = dkey(qa, qb, sqn, PA[base+slot], PB[base+slot]);
    skey[w][i] = u;
  }

  // final: exact top-16 over survivors (u64 = key||slot, ascending, slot tie-break)
  unsigned long long vbest;
  {
    unsigned long long v = ~0ull;
    if (lane < cnt) v = ((unsigned long long)skey[w][lane] << 32) | sslot[w][lane];
    vbest = bsort64(v, lane);
  }
  for (int c=1; c*64 < cnt; ++c){   // cold path (cnt>64 ~ never)
    const int i = c*64 + lane;
    unsigned long long v = ~0ull;
    if (i < cnt) v = ((unsigned long long)skey[w][i] << 32) | sslot[w][i];
    v = bsort64(v, lane);
    const unsigned long long r = __shfl(v, 63-lane);
    vbest = vbest < r ? vbest : r;     // bitonic sequence of the 64 smallest
#pragma unroll
    for (int j=32;j>0;j>>=1){          // cleanup merge, ascending
      const unsigned long long o = __shfl_xor(vbest, j);
      const bool keepMin = (lane & j) == 0;
      const unsigned long long mn = vbest < o ? vbest : o;
      const unsigned long long mx = vbest < o ? o : vbest;
      vbest = keepMin ? mn : mx;
    }
  }
  if (lane < 16) nbr[n*16 + lane] = base + (int)(vbest & 0xFFFFFFFFull);
}

// ---------------- layer-1 GEMM: x[NN,6] @ W1[6,256] ----------------
__global__ __launch_bounds__(256) void gemm_in6(const float* __restrict__ x, const float* __restrict__ W,
                                                float* __restrict__ h){
  const int t = blockIdx.x*256 + threadIdx.x;  // over NN*64
  const int n = t >> 6, cg = t & 63;
  const float* xr = x + n*6;
  float xv[6];
#pragma unroll
  for (int d=0; d<6; d++) xv[d] = xr[d];
  float4 acc = make_float4(0.f,0.f,0.f,0.f);
#pragma unroll
  for (int d=0; d<6; d++){
    const float4 wv = *(const float4*)(W + d*256 + cg*4);
    acc.x += xv[d]*wv.x; acc.y += xv[d]*wv.y; acc.z += xv[d]*wv.z; acc.w += xv[d]*wv.w;
  }
  *(float4*)(h + n*256 + cg*4) = acc;
}

// ---------------- residual: y[NN,128] += x@res_W + res_b ----------------
__global__ __launch_bounds__(256) void res_k(const float* __restrict__ x, const float* __restrict__ W,
                                             const float* __restrict__ b, float* __restrict__ y){
  const int t = blockIdx.x*256 + threadIdx.x;  // over NN*128
  const int n = t >> 7, c = t & 127;
  const float* xr = x + n*6;
  float acc = b[c];
#pragma unroll
  for (int d=0; d<6; d++) acc += xr[d]*W[d*128 + c];
  y[t] += acc;
}

// ---------------- attention logits: als/ald [NN,HEADS] ----------------
template<int HEADS, int C>
__global__ __launch_bounds__(256) void al_k(const float* __restrict__ h, const float* __restrict__ asrc,
                                            const float* __restrict__ adst, float* __restrict__ als,
                                            float* __restrict__ ald){
  const int t = blockIdx.x*256 + threadIdx.x;  // over NN*HEADS
  const int n = t / HEADS, hd = t % HEADS;
  const float* hp = h + (n*HEADS + hd)*C;
  const float* ap = asrc + hd*C;
  const float* dp = adst + hd*C;
  float s=0.f, d=0.f;
#pragma unroll 4
  for (int c=0;c<C;c+=4){
    const float4 v = *(const float4*)(hp+c);
    const float4 a = *(const float4*)(ap+c);
    const float4 b = *(const float4*)(dp+c);
    s += v.x*a.x + v.y*a.y + v.z*a.z + v.w*a.w;
    d += v.x*b.x + v.y*b.y + v.z*b.z + v.w*b.w;
  }
  als[t] = s; ald[t] = d;
}

// ---------------- GAT aggregation: one wave per node, 17-way softmax gather ----------------
template<int HEADS, int C>
__global__ __launch_bounds__(256) void agg_k(const float* __restrict__ h, const float* __restrict__ als,
                                             const float* __restrict__ ald, const int* __restrict__ nbr,
                                             const float* __restrict__ bias, float* __restrict__ out){
  constexpr int CT = HEADS*C;
  constexpr int F  = CT/64;
  const int w = threadIdx.x >> 6, lane = threadIdx.x & 63;
  const int n = blockIdx.x*4 + w;
  const int head = (lane*F)/C;
  const int col  = lane*F;
  const int nb = nbr[n*16 + (lane & 15)];
  const float aldn = ald[n*HEADS + head];
  float e[17];
#pragma unroll
  for (int j=0;j<17;j++){
    const int sj = (j<16) ? __shfl(nb, j) : n;
    const float v = als[sj*HEADS + head] + aldn;
    e[j] = v > 0.f ? v : 0.2f*v;
  }
  float mx = e[0];
#pragma unroll
  for (int j=1;j<17;j++) mx = fmaxf(mx, e[j]);
  float den = 0.f;
#pragma unroll
  for (int j=0;j<17;j++){ e[j] = expf(e[j]-mx); den += e[j]; }
  float acc[F];
#pragma unroll
  for (int f=0;f<F;f++) acc[f]=0.f;
#pragma unroll
  for (int j=0;j<17;j++){
    const int sj = (j<16) ? __shfl(nb, j) : n;
    const float* hp = h + sj*CT + col;
    if constexpr (F==4){
      const float4 v = *(const float4*)hp;
      acc[0] += e[j]*v.x; acc[1] += e[j]*v.y; acc[2] += e[j]*v.z; acc[3] += e[j]*v.w;
    } else {
      const float2 v = *(const float2*)hp;
      acc[0] += e[j]*v.x; acc[1] += e[j]*v.y;
    }
  }
  const float inv = 1.f/den;
  if constexpr (F==4){
    float4 o;
    o.x = gelu_f(acc[0]*inv + bias[col+0]);
    o.y = gelu_f(acc[1]*inv + bias[col+1]);
    o.z = gelu_f(acc[2]*inv + bias[col+2]);
    o.w = gelu_f(acc[3]*inv + bias[col+3]);
    *(float4*)(out + n*CT + col) = o;
  } else {
    float2 o;
    o.x = gelu_f(acc[0]*inv + bias[col+0]);
    o.y = gelu_f(acc[1]*inv + bias[col+1]);
    *(float2*)(out + n*CT + col) = o;
  }
}

// ---------------- generic fp32 tiled GEMM: [M,KC] @ [KC,NC], BM=128 BN=64 BK=32 ----------------
template<int KC, int NC, bool BIAS, bool GELU>
__global__ __launch_bounds__(256) void gemm_k(const float* __restrict__ A, const float* __restrict__ B,
                                              const float* __restrict__ bias, float* __restrict__ C){
  __shared__ float Ast[32][132];   // A chunk transposed: Ast[k][row]
  __shared__ float Bs[32][64];
  const int t  = threadIdx.x;
  const int r0 = blockIdx.x*128;
  const int c0 = blockIdx.y*64;
  const int ty = t >> 4, tx = t & 15;
  const int ar = t >> 1, ac = (t & 1)*16;
  const int br = t >> 3, bc = (t & 7)*8;
  float acc[8][4];
#pragma unroll
  for (int i=0;i<8;i++)
#pragma unroll
    for (int j=0;j<4;j++) acc[i][j] = 0.f;

#pragma unroll 1
  for (int kc=0; kc<KC; kc+=32){
    const float* Ap = A + (size_t)(r0+ar)*KC + kc + ac;
    float4 av[4];
#pragma unroll
    for (int u=0;u<4;u++) av[u] = *(const float4*)(Ap + u*4);
#pragma unroll
    for (int u=0;u<4;u++){
      Ast[ac+u*4+0][ar] = av[u].x;
      Ast[ac+u*4+1][ar] = av[u].y;
      Ast[ac+u*4+2][ar] = av[u].z;
      Ast[ac+u*4+3][ar] = av[u].w;
    }
    const float* Bp = B + (size_t)(kc+br)*NC + c0 + bc;
    *(float4*)&Bs[br][bc]   = *(const float4*)Bp;
    *(float4*)&Bs[br][bc+4] = *(const float4*)(Bp+4);
    __syncthreads();
#pragma unroll
    for (int k=0;k<32;k++){
      const float4 a0 = *(const float4*)&Ast[k][ty*8];
      const float4 a1 = *(const float4*)&Ast[k][ty*8+4];
      const float4 bv = *(const float4*)&Bs[k][tx*4];
      const float avr[8] = {a0.x,a0.y,a0.z,a0.w,a1.x,a1.y,a1.z,a1.w};
      const float bbr[4] = {bv.x,bv.y,bv.z,bv.w};
#pragma unroll
      for (int i=0;i<8;i++)
#pragma unroll
        for (int j=0;j<4;j++)
          acc[i][j] += avr[i]*bbr[j];
    }
    __syncthreads();
  }
#pragma unroll
  for (int i=0;i<8;i++){
    const int r = r0 + ty*8 + i;
    float vv[4];
#pragma unroll
    for (int j=0;j<4;j++){
      float v = acc[i][j];
      if constexpr (BIAS) v += bias[c0 + tx*4 + j];
      if constexpr (GELU) v = gelu_f(v);
      vv[j] = v;
    }
    *(float4*)(C + (size_t)r*NC + c0 + tx*4) = make_float4(vv[0],vv[1],vv[2],vv[3]);
  }
}

// ---------------- final tiny GEMM: [NN,64] @ [64,6] + b ----------------
__global__ __launch_bounds__(256) void m3_k(const float* __restrict__ A, const float* __restrict__ W,
                                            const float* __restrict__ bias, float* __restrict__ out){
  __shared__ float Wl[64*6];
  __shared__ float bl[6];
  const int t = threadIdx.x;
  for (int i=t; i<384; i+=256) Wl[i] = W[i];
  if (t < 6) bl[t] = bias[t];
  __syncthreads();
  const int n = blockIdx.x*256 + t;
  const float* ap = A + n*64;
  float acc[6] = {0.f,0.f,0.f,0.f,0.f,0.f};
  for (int k=0;k<64;k+=4){
    const float4 v = *(const float4*)(ap+k);
    const float vr[4] = {v.x,v.y,v.z,v.w};
#pragma unroll
    for (int u=0;u<4;u++)
#pragma unroll
      for (int j=0;j<6;j++)
        acc[j] += vr[u]*Wl[(k+u)*6+j];
  }
#pragma unroll
  for (int j=0;j<6;j++) out[n*6+j] = acc[j] + bl[j];
}

extern "C" void kernel_launch(void* const* d_in, const int* in_sizes, int n_in,
                              void* d_out, int out_size, void* d_ws, size_t ws_size,
                              hipStream_t stream){
  (void)in_sizes; (void)n_in; (void)out_size; (void)ws_size;
  const float* x      = (const float*)d_in[0];
  const float* W1     = (const float*)d_in[1];
  const float* a_src1 = (const float*)d_in[2];
  const float* a_dst1 = (const float*)d_in[3];
  const float* b1     = (const float*)d_in[4];
  const float* W2     = (const float*)d_in[5];
  const float* a_src2 = (const float*)d_in[6];
  const float* a_dst2 = (const float*)d_in[7];
  const float* b2     = (const float*)d_in[8];
  const float* W3     = (const float*)d_in[9];
  const float* a_src3 = (const float*)d_in[10];
  const float* a_dst3 = (const float*)d_in[11];
  const float* b3     = (const float*)d_in[12];
  const float* res_W  = (const float*)d_in[13];
  const float* res_b  = (const float*)d_in[14];
  const float* m1_W   = (const float*)d_in[15];
  const float* m1_b   = (const float*)d_in[16];
  const float* m2_W   = (const float*)d_in[17];
  const float* m2_b   = (const float*)d_in[18];
  const float* m3_W   = (const float*)d_in[19];
  const float* m3_b   = (const float*)d_in[20];
  float* out = (float*)d_out;

  char* wsb = (char*)d_ws;
  int*   nbr = (int*)wsb;                                   // 1 MB
  float* H   = (float*)(wsb + (1u<<20));                    // 16 MB
  float* Y   = (float*)(wsb + (1u<<20) + (16u<<20));        // 16 MB
  float* ALS = (float*)(wsb + (1u<<20) + (32u<<20));        // 256 KB
  float* ALD = ALS + NN*4;                                  // 256 KB
  float4* PA = (float4*)(wsb + (1u<<20) + (32u<<20) + (512u<<10)); // 256 KB
  float4* PB = PA + NN;                                            // 256 KB

  pack_k<<<NN/256, 256, 0, stream>>>(x, PA, PB);
  knn_k<<<NN/4, 256, 0, stream>>>(PA, PB, nbr);

  // GAT layer 1: 6 -> 4x64
  gemm_in6<<<NN*64/256, 256, 0, stream>>>(x, W1, H);
  al_k<4,64><<<NN*4/256, 256, 0, stream>>>(H, a_src1, a_dst1, ALS, ALD);
  agg_k<4,64><<<NN/4, 256, 0, stream>>>(H, ALS, ALD, nbr, b1, Y);

  // GAT layer 2: 256 -> 4x64
  gemm_k<256,256,false,false><<<dim3(NN/128, 4), 256, 0, stream>>>(Y, W2, nullptr, H);
  al_k<4,64><<<NN*4/256, 256, 0, stream>>>(H, a_src2, a_dst2, ALS, ALD);
  agg_k<4,64><<<NN/4, 256, 0, stream>>>(H, ALS, ALD, nbr, b2, Y);

  // GAT layer 3: 256 -> 1x128
  gemm_k<256,128,false,false><<<dim3(NN/128, 2), 256, 0, stream>>>(Y, W3, nullptr, H);
  al_k<1,128><<<NN/256, 256, 0, stream>>>(H, a_src3, a_dst3, ALS, ALD);
  agg_k<1,128><<<NN/4, 256, 0, stream>>>(H, ALS, ALD, nbr, b3, Y);

  // residual + MLP
  res_k<<<NN*128/256, 256, 0, stream>>>(x, res_W, res_b, Y);
  gemm_k<128,128,true,true><<<dim3(NN/128, 2), 256, 0, stream>>>(Y, m1_W, m1_b, H);
  gemm_k<128,64,true,true><<<dim3(NN/128, 1), 256, 0, stream>>>(H, m2_W, m2_b, Y);
  m3_k<<<NN/256, 256, 0, stream>>>(Y, m3_W, m3_b, out);
}

// Round 8
// 268.553 us; speedup vs baseline: 1.1241x; 1.0021x over previous
//
#include <hip/hip_runtime.h>
#include <math.h>

#define NN 16384      // B*N total nodes
#define NPB 4096      // nodes per batch
#define KCAP 128      // survivor capacity per wave (expected ~20)
#define TS 512        // kNN candidate tile size (LDS 20480 B)

__device__ __forceinline__ float gelu_f(float v){
  return 0.5f*v*(1.0f+erff(v*0.70710678118654752440f));
}

// monotone float->uint map: order-preserving for all finite values
__device__ __forceinline__ unsigned fmap(float d2){
  unsigned u = __float_as_uint(d2);
  return u ^ ((unsigned)((int)u >> 31) | 0x80000000u);
}

// distance key: one canonical inlined form so pass-1 and the survivor recompute
// produce bit-identical values
__device__ __forceinline__ unsigned dkey(const float4 qa, const float4 qb, const float sqn,
                                         const float4 a, const float4 b){
  const float dot = qa.x*a.x + qa.y*a.y + qa.z*a.z + qa.w*a.w + qb.x*b.x + qb.y*b.y;
  const float d2 = sqn + b.z - 2.0f*dot;
  return fmap(d2);
}

// ascending-by-lane bitonic sort of one u64 per lane across the 64-lane wave
__device__ __forceinline__ unsigned long long bsort64(unsigned long long v, int lane){
#pragma unroll
  for (int k=2;k<=64;k<<=1){
#pragma unroll
    for (int j=k>>1;j>0;j>>=1){
      const unsigned long long o = __shfl_xor(v, j);
      const bool keepMin = ((lane & k) == 0) == ((lane & j) == 0);
      const unsigned long long mn = v < o ? v : o;
      const unsigned long long mx = v < o ? o : v;
      v = keepMin ? mn : mx;
    }
  }
  return v;
}

// ascending-by-lane bitonic sort of one u32 per lane
__device__ __forceinline__ unsigned bsort32(unsigned v, int lane){
#pragma unroll
  for (int k=2;k<=64;k<<=1){
#pragma unroll
    for (int j=k>>1;j>0;j>>=1){
      const unsigned o = __shfl_xor(v, j);
      const bool keepMin = ((lane & k) == 0) == ((lane & j) == 0);
      const unsigned mn = v < o ? v : o;
      const unsigned mx = v < o ? o : v;
      v = keepMin ? mn : mx;
    }
  }
  return v;
}

// ---------------- pack: x[NN,6] -> PA[NN]={x0..x3}, PB[NN]={x4,x5,sq,0} ----------------
__global__ __launch_bounds__(256) void pack_k(const float* __restrict__ x,
                                              float4* __restrict__ PA, float4* __restrict__ PB){
  const int n = blockIdx.x*256 + threadIdx.x;
  const float* xr = x + (size_t)n*6;
  const float x0=xr[0],x1=xr[1],x2=xr[2],x3=xr[3],x4=xr[4],x5=xr[5];
  const float sq = x0*x0+x1*x1+x2*x2+x3*x3+x4*x4+x5*x5;
  PA[n] = make_float4(x0,x1,x2,x3);
  PB[n] = make_float4(x4,x5,sq,0.f);
}

// ---------------- kNN v8: v7 structure, NO launch_bounds (R7's (256,6) still partially
//                  spilled kp[32] -> 40 VGPR + 52 MB scratch traffic; R4 precedent shows
//                  unconstrained allocator keeps key arrays in VGPRs). ----------------
__global__ void knn_k(const float4* __restrict__ PA, const float4* __restrict__ PB,
                      int* __restrict__ nbr){
  __shared__ float4 A4[TS];
  __shared__ float4 B4[TS];
  __shared__ unsigned skey[4][KCAP];
  __shared__ unsigned sslot[4][KCAP];
  const int t = threadIdx.x, w = t >> 6, lane = t & 63;
  const int n = blockIdx.x*4 + w;
  const int base = n & ~(NPB-1);
  const float4 qa = PA[n];
  const float4 qb = PB[n];
  const float sqn = qb.z;
  const int selfslot = n - base;

  // single pass: distances -> 16-bit packed keys in regs + full-precision lane min
  unsigned kp[32];
  unsigned minu = 0xFFFFFFFFu;
#pragma unroll
  for (int tile=0; tile<NPB/TS; ++tile){
    __syncthreads();   // all waves done reading previous tile
#pragma unroll
    for (int i=t; i<TS; i+=256){
      A4[i] = PA[base+tile*TS+i];
      B4[i] = PB[base+tile*TS+i];
    }
    __syncthreads();
    unsigned lo = 0;
#pragma unroll
    for (int it=0; it<TS/64; ++it){
      const int s = it*64 + lane;
      unsigned u = dkey(qa, qb, sqn, A4[s], B4[s]);
      if (tile*TS + s == selfslot) u = 0xFFFFFFFFu;   // exclude self
      minu = u < minu ? u : minu;
      if ((it & 1) == 0) lo = u >> 16;
      else               kp[(tile*(TS/64)+it)>>1] = lo | (u & 0xFFFF0000u);
    }
  }

  // pivot: 16th smallest lane-min (self excluded in-pass) >= true 16th key
  unsigned T = bsort32(minu, lane);
  T = __shfl(T, 15);
  const unsigned T16 = T >> 16;

  // compact survivors (truncated key <= T16 -> superset of true top-16)
  int cnt = 0;
#pragma unroll
  for (int q=0; q<64; ++q){
    const unsigned k16 = (kp[q>>1] >> ((q&1)*16)) & 0xFFFFu;
    const bool p = k16 <= T16;
    const unsigned long long bb = __ballot(p);
    if (p){
      const int pos = cnt + (int)__popcll(bb & ((1ull << lane) - 1ull));
      if (pos < KCAP){
        // q = tile*8 + it ; slot = tile*TS + it*64 + lane
        sslot[w][pos] = (unsigned)((q>>3)*TS + (q&7)*64 + lane);
      }
    }
    cnt += (int)__popcll(bb);
  }
  if (cnt > KCAP) cnt = KCAP;

  // recompute exact keys for survivors (identical expression -> identical bits)
  for (int i=lane; i<cnt; i+=64){
    const int slot = (int)sslot[w][i];
    unsigned u = dkey(qa, qb, sqn, PA[base+slot], PB[base+slot]);
    skey[w][i] = u;
  }

  // final: exact top-16 over survivors (u64 = key||slot, ascending, slot tie-break)
  unsigned long long vbest;
  {
    unsigned long long v = ~0ull;
    if (lane < cnt) v = ((unsigned long long)skey[w][lane] << 32) | sslot[w][lane];
    vbest = bsort64(v, lane);
  }
  for (int c=1; c*64 < cnt; ++c){   // cold path (cnt>64 ~ never)
    const int i = c*64 + lane;
    unsigned long long v = ~0ull;
    if (i < cnt) v = ((unsigned long long)skey[w][i] << 32) | sslot[w][i];
    v = bsort64(v, lane);
    const unsigned long long r = __shfl(v, 63-lane);
    vbest = vbest < r ? vbest : r;     // bitonic sequence of the 64 smallest
#pragma unroll
    for (int j=32;j>0;j>>=1){          // cleanup merge, ascending
      const unsigned long long o = __shfl_xor(vbest, j);
      const bool keepMin = (lane & j) == 0;
      const unsigned long long mn = vbest < o ? vbest : o;
      const unsigned long long mx = vbest < o ? o : vbest;
      vbest = keepMin ? mn : mx;
    }
  }
  if (lane < 16) nbr[n*16 + lane] = base + (int)(vbest & 0xFFFFFFFFull);
}

// ---------------- layer-1 GEMM: x[NN,6] @ W1[6,256] ----------------
__global__ __launch_bounds__(256) void gemm_in6(const float* __restrict__ x, const float* __restrict__ W,
                                                float* __restrict__ h){
  const int t = blockIdx.x*256 + threadIdx.x;  // over NN*64
  const int n = t >> 6, cg = t & 63;
  const float* xr = x + n*6;
  float xv[6];
#pragma unroll
  for (int d=0; d<6; d++) xv[d] = xr[d];
  float4 acc = make_float4(0.f,0.f,0.f,0.f);
#pragma unroll
  for (int d=0; d<6; d++){
    const float4 wv = *(const float4*)(W + d*256 + cg*4);
    acc.x += xv[d]*wv.x; acc.y += xv[d]*wv.y; acc.z += xv[d]*wv.z; acc.w += xv[d]*wv.w;
  }
  *(float4*)(h + n*256 + cg*4) = acc;
}

// ---------------- attention logits: als/ald [NN,HEADS] ----------------
template<int HEADS, int C>
__global__ __launch_bounds__(256) void al_k(const float* __restrict__ h, const float* __restrict__ asrc,
                                            const float* __restrict__ adst, float* __restrict__ als,
                                            float* __restrict__ ald){
  const int t = blockIdx.x*256 + threadIdx.x;  // over NN*HEADS
  const int n = t / HEADS, hd = t % HEADS;
  const float* hp = h + (n*HEADS + hd)*C;
  const float* ap = asrc + hd*C;
  const float* dp = adst + hd*C;
  float s=0.f, d=0.f;
#pragma unroll 4
  for (int c=0;c<C;c+=4){
    const float4 v = *(const float4*)(hp+c);
    const float4 a = *(const float4*)(ap+c);
    const float4 b = *(const float4*)(dp+c);
    s += v.x*a.x + v.y*a.y + v.z*a.z + v.w*a.w;
    d += v.x*b.x + v.y*b.y + v.z*b.z + v.w*b.w;
  }
  als[t] = s; ald[t] = d;
}

// ---------------- GAT aggregation: one wave per node, 17-way softmax gather;
//                  RES fuses the x@res_W + res_b residual (layer 3) ----------------
template<int HEADS, int C, bool RES>
__global__ __launch_bounds__(256) void agg_k(const float* __restrict__ h, const float* __restrict__ als,
                                             const float* __restrict__ ald, const int* __restrict__ nbr,
                                             const float* __restrict__ bias, float* __restrict__ out,
                                             const float* __restrict__ xin, const float* __restrict__ rW,
                                             const float* __restrict__ rb){
  constexpr int CT = HEADS*C;
  constexpr int F  = CT/64;
  const int w = threadIdx.x >> 6, lane = threadIdx.x & 63;
  const int n = blockIdx.x*4 + w;
  const int head = (lane*F)/C;
  const int col  = lane*F;
  const int nb = nbr[n*16 + (lane & 15)];
  const float aldn = ald[n*HEADS + head];
  float e[17];
#pragma unroll
  for (int j=0;j<17;j++){
    const int sj = (j<16) ? __shfl(nb, j) : n;
    const float v = als[sj*HEADS + head] + aldn;
    e[j] = v > 0.f ? v : 0.2f*v;
  }
  float mx = e[0];
#pragma unroll
  for (int j=1;j<17;j++) mx = fmaxf(mx, e[j]);
  float den = 0.f;
#pragma unroll
  for (int j=0;j<17;j++){ e[j] = expf(e[j]-mx); den += e[j]; }
  float acc[F];
#pragma unroll
  for (int f=0;f<F;f++) acc[f]=0.f;
#pragma unroll
  for (int j=0;j<17;j++){
    const int sj = (j<16) ? __shfl(nb, j) : n;
    const float* hp = h + sj*CT + col;
    if constexpr (F==4){
      const float4 v = *(const float4*)hp;
      acc[0] += e[j]*v.x; acc[1] += e[j]*v.y; acc[2] += e[j]*v.z; acc[3] += e[j]*v.w;
    } else {
      const float2 v = *(const float2*)hp;
      acc[0] += e[j]*v.x; acc[1] += e[j]*v.y;
    }
  }
  const float inv = 1.f/den;
  if constexpr (F==4){
    float4 o;
    o.x = gelu_f(acc[0]*inv + bias[col+0]);
    o.y = gelu_f(acc[1]*inv + bias[col+1]);
    o.z = gelu_f(acc[2]*inv + bias[col+2]);
    o.w = gelu_f(acc[3]*inv + bias[col+3]);
    *(float4*)(out + n*CT + col) = o;
  } else {
    float2 o;
    o.x = gelu_f(acc[0]*inv + bias[col+0]);
    o.y = gelu_f(acc[1]*inv + bias[col+1]);
    if constexpr (RES){
      const float* xr = xin + (size_t)n*6;
      float r0 = rb[col+0], r1 = rb[col+1];
#pragma unroll
      for (int d=0; d<6; d++){
        const float xv = xr[d];
        r0 += xv*rW[d*128 + col+0];
        r1 += xv*rW[d*128 + col+1];
      }
      o.x += r0; o.y += r1;
    }
    *(float2*)(out + n*CT + col) = o;
  }
}

// ---------------- generic fp32 tiled GEMM: [M,KC] @ [KC,NC], BM=128 BN=64 BK=32 ----------------
template<int KC, int NC, bool BIAS, bool GELU>
__global__ __launch_bounds__(256) void gemm_k(const float* __restrict__ A, const float* __restrict__ B,
                                              const float* __restrict__ bias, float* __restrict__ C){
  __shared__ float Ast[32][132];   // A chunk transposed: Ast[k][row]
  __shared__ float Bs[32][64];
  const int t  = threadIdx.x;
  const int r0 = blockIdx.x*128;
  const int c0 = blockIdx.y*64;
  const int ty = t >> 4, tx = t & 15;
  const int ar = t >> 1, ac = (t & 1)*16;
  const int br = t >> 3, bc = (t & 7)*8;
  float acc[8][4];
#pragma unroll
  for (int i=0;i<8;i++)
#pragma unroll
    for (int j=0;j<4;j++) acc[i][j] = 0.f;

#pragma unroll 1
  for (int kc=0; kc<KC; kc+=32){
    const float* Ap = A + (size_t)(r0+ar)*KC + kc + ac;
    float4 av[4];
#pragma unroll
    for (int u=0;u<4;u++) av[u] = *(const float4*)(Ap + u*4);
#pragma unroll
    for (int u=0;u<4;u++){
      Ast[ac+u*4+0][ar] = av[u].x;
      Ast[ac+u*4+1][ar] = av[u].y;
      Ast[ac+u*4+2][ar] = av[u].z;
      Ast[ac+u*4+3][ar] = av[u].w;
    }
    const float* Bp = B + (size_t)(kc+br)*NC + c0 + bc;
    *(float4*)&Bs[br][bc]   = *(const float4*)Bp;
    *(float4*)&Bs[br][bc+4] = *(const float4*)(Bp+4);
    __syncthreads();
#pragma unroll
    for (int k=0;k<32;k++){
      const float4 a0 = *(const float4*)&Ast[k][ty*8];
      const float4 a1 = *(const float4*)&Ast[k][ty*8+4];
      const float4 bv = *(const float4*)&Bs[k][tx*4];
      const float avr[8] = {a0.x,a0.y,a0.z,a0.w,a1.x,a1.y,a1.z,a1.w};
      const float bbr[4] = {bv.x,bv.y,bv.z,bv.w};
#pragma unroll
      for (int i=0;i<8;i++)
#pragma unroll
        for (int j=0;j<4;j++)
          acc[i][j] += avr[i]*bbr[j];
    }
    __syncthreads();
  }
#pragma unroll
  for (int i=0;i<8;i++){
    const int r = r0 + ty*8 + i;
    float vv[4];
#pragma unroll
    for (int j=0;j<4;j++){
      float v = acc[i][j];
      if constexpr (BIAS) v += bias[c0 + tx*4 + j];
      if constexpr (GELU) v = gelu_f(v);
      vv[j] = v;
    }
    *(float4*)(C + (size_t)r*NC + c0 + tx*4) = make_float4(vv[0],vv[1],vv[2],vv[3]);
  }
}

// ---------------- final tiny GEMM: [NN,64] @ [64,6] + b ----------------
__global__ __launch_bounds__(256) void m3_k(const float* __restrict__ A, const float* __restrict__ W,
                                            const float* __restrict__ bias, float* __restrict__ out){
  __shared__ float Wl[64*6];
  __shared__ float bl[6];
  const int t = threadIdx.x;
  for (int i=t; i<384; i+=256) Wl[i] = W[i];
  if (t < 6) bl[t] = bias[t];
  __syncthreads();
  const int n = blockIdx.x*256 + t;
  const float* ap = A + n*64;
  float acc[6] = {0.f,0.f,0.f,0.f,0.f,0.f};
  for (int k=0;k<64;k+=4){
    const float4 v = *(const float4*)(ap+k);
    const float vr[4] = {v.x,v.y,v.z,v.w};
#pragma unroll
    for (int u=0;u<4;u++)
#pragma unroll
      for (int j=0;j<6;j++)
        acc[j] += vr[u]*Wl[(k+u)*6+j];
  }
#pragma unroll
  for (int j=0;j<6;j++) out[n*6+j] = acc[j] + bl[j];
}

extern "C" void kernel_launch(void* const* d_in, const int* in_sizes, int n_in,
                              void* d_out, int out_size, void* d_ws, size_t ws_size,
                              hipStream_t stream){
  (void)in_sizes; (void)n_in; (void)out_size; (void)ws_size;
  const float* x      = (const float*)d_in[0];
  const float* W1     = (const float*)d_in[1];
  const float* a_src1 = (const float*)d_in[2];
  const float* a_dst1 = (const float*)d_in[3];
  const float* b1     = (const float*)d_in[4];
  const float* W2     = (const float*)d_in[5];
  const float* a_src2 = (const float*)d_in[6];
  const float* a_dst2 = (const float*)d_in[7];
  const float* b2     = (const float*)d_in[8];
  const float* W3     = (const float*)d_in[9];
  const float* a_src3 = (const float*)d_in[10];
  const float* a_dst3 = (const float*)d_in[11];
  const float* b3     = (const float*)d_in[12];
  const float* res_W  = (const float*)d_in[13];
  const float* res_b  = (const float*)d_in[14];
  const float* m1_W   = (const float*)d_in[15];
  const float* m1_b   = (const float*)d_in[16];
  const float* m2_W   = (const float*)d_in[17];
  const float* m2_b   = (const float*)d_in[18];
  const float* m3_W   = (const float*)d_in[19];
  const float* m3_b   = (const float*)d_in[20];
  float* out = (float*)d_out;

  char* wsb = (char*)d_ws;
  int*   nbr = (int*)wsb;                                   // 1 MB
  float* H   = (float*)(wsb + (1u<<20));                    // 16 MB
  float* Y   = (float*)(wsb + (1u<<20) + (16u<<20));        // 16 MB
  float* ALS = (float*)(wsb + (1u<<20) + (32u<<20));        // 256 KB
  float* ALD = ALS + NN*4;                                  // 256 KB
  float4* PA = (float4*)(wsb + (1u<<20) + (32u<<20) + (512u<<10)); // 256 KB
  float4* PB = PA + NN;                                            // 256 KB

  pack_k<<<NN/256, 256, 0, stream>>>(x, PA, PB);
  knn_k<<<NN/4, 256, 0, stream>>>(PA, PB, nbr);

  // GAT layer 1: 6 -> 4x64
  gemm_in6<<<NN*64/256, 256, 0, stream>>>(x, W1, H);
  al_k<4,64><<<NN*4/256, 256, 0, stream>>>(H, a_src1, a_dst1, ALS, ALD);
  agg_k<4,64,false><<<NN/4, 256, 0, stream>>>(H, ALS, ALD, nbr, b1, Y, nullptr, nullptr, nullptr);

  // GAT layer 2: 256 -> 4x64
  gemm_k<256,256,false,false><<<dim3(NN/128, 4), 256, 0, stream>>>(Y, W2, nullptr, H);
  al_k<4,64><<<NN*4/256, 256, 0, stream>>>(H, a_src2, a_dst2, ALS, ALD);
  agg_k<4,64,false><<<NN/4, 256, 0, stream>>>(H, ALS, ALD, nbr, b2, Y, nullptr, nullptr, nullptr);

  // GAT layer 3: 256 -> 1x128, residual fused
  gemm_k<256,128,false,false><<<dim3(NN/128, 2), 256, 0, stream>>>(Y, W3, nullptr, H);
  al_k<1,128><<<NN/256, 256, 0, stream>>>(H, a_src3, a_dst3, ALS, ALD);
  agg_k<1,128,true><<<NN/4, 256, 0, stream>>>(H, ALS, ALD, nbr, b3, Y, x, res_W, res_b);

  // MLP
  gemm_k<128,128,true,true><<<dim3(NN/128, 2), 256, 0, stream>>>(Y, m1_W, m1_b, H);
  gemm_k<128,64,true,true><<<dim3(NN/128, 1), 256, 0, stream>>>(H, m2_W, m2_b, Y);
  m3_k<<<NN/256, 256, 0, stream>>>(Y, m3_W, m3_b, out);
}